// Round 1
// baseline (223.992 us; speedup 1.0000x reference)
//
#include <hip/hip_runtime.h>
#include <math.h>

#define DX 192
#define DY 192
#define DZ 128
#define DB 4
#define DXY (DX*DY)          // 36864
#define NTOT (DB*DZ*DXY)     // 18874368
#define NV (NTOT/4)          // 4718592 vec4 groups
#define XV (DX/4)            // 48

// ws layout (doubles): [0..12] sum(di*dt), [13..25] sum(dt*dt), [26] bce sum

__device__ inline float wred(float v) {
    #pragma unroll
    for (int o = 32; o > 0; o >>= 1) v += __shfl_down(v, o, 64);
    return v;
}

__global__ __launch_bounds__(256) void gc3d_main(const float* __restrict__ inp,
                                                 const float* __restrict__ tgt,
                                                 double* __restrict__ acc) {
    float s0=0,s1=0,s2=0,s3=0,s4=0,s5=0,s6=0,s7=0,s8=0,s9=0,s10=0,s11=0,s12=0;
    float r0=0,r1=0,r2=0,r3=0,r4=0,r5=0,r6=0,r7=0,r8=0,r9=0,r10=0,r11=0,r12=0;
    float bces = 0.f;

    int tid = blockIdx.x * blockDim.x + threadIdx.x;
    int stride = gridDim.x * blockDim.x;

    for (int v = tid; v < NV; v += stride) {
        int xv4 = v % XV;
        int rem = v / XV;           // global row index over DB*DZ*DY
        int y = rem % DY;
        int z = (rem / DY) % DZ;
        int x0 = xv4 * 4;

        bool zv = (z != DZ - 1);
        bool yv = (y != DY - 1);
        int oz = zv ? DXY : 0;
        int oy = yv ? DX : 0;
        int xe = (x0 != DX - 4) ? 4 : 3;    // clamped +4 scalar offset
        float fz = zv ? 1.f : 0.f;
        float fy = yv ? 1.f : 0.f;
        float fx3 = (x0 != DX - 4) ? 1.f : 0.f;   // x-validity of element 3

        long base = (long)v * 4;    // == rem*DX + x0
        const float* ip = inp + base;
        const float* tp = tgt + base;

        float4 i00 = *(const float4*)(ip);
        float4 i01 = *(const float4*)(ip + oy);
        float4 i10 = *(const float4*)(ip + oz);
        float4 i11 = *(const float4*)(ip + oz + oy);
        float4 t00 = *(const float4*)(tp);
        float4 t01 = *(const float4*)(tp + oy);
        float4 t10 = *(const float4*)(tp + oz);
        float4 t11 = *(const float4*)(tp + oz + oy);
        float i00e = ip[xe],        i01e = ip[oy + xe];
        float i10e = ip[oz + xe],   i11e = ip[oz + oy + xe];
        float t00e = tp[xe],        t01e = tp[oy + xe];
        float t10e = tp[oz + xe],   t11e = tp[oz + oy + xe];

        // corners: c0=(0,0,0) c1=(0,0,1) c2=(0,1,0) c3=(0,1,1)
        //          c4=(1,0,0) c5=(1,0,1) c6=(1,1,0) c7=(1,1,1)  (z,y,x)
        // 13 normalized offsets -> corner pairs (a,b) + mask dims
        #define PROC_ELEM(c0,c1,c2,c3,c4,c5,c6,c7, d0,d1,d2,d3,d4,d5,d6,d7, FX) do { \
            float fzy = fz*fy, fyx = fy*(FX), fzx = fz*(FX), fzyx = fzy*(FX); \
            float di, dt, dtm; \
            di=c4-c0; dt=d4-d0; dtm=fz  *dt; s0 +=di*dtm; r0 +=dt*dtm; \
            di=c2-c0; dt=d2-d0; dtm=fy  *dt; s1 +=di*dtm; r1 +=dt*dtm; \
            di=c1-c0; dt=d1-d0; dtm=(FX)*dt; s2 +=di*dtm; r2 +=dt*dtm; \
            di=c6-c0; dt=d6-d0; dtm=fzy *dt; s3 +=di*dtm; r3 +=dt*dtm; \
            di=c4-c2; dt=d4-d2; dtm=fzy *dt; s4 +=di*dtm; r4 +=dt*dtm; \
            di=c3-c0; dt=d3-d0; dtm=fyx *dt; s5 +=di*dtm; r5 +=dt*dtm; \
            di=c2-c1; dt=d2-d1; dtm=fyx *dt; s6 +=di*dtm; r6 +=dt*dtm; \
            di=c4-c1; dt=d4-d1; dtm=fzx *dt; s7 +=di*dtm; r7 +=dt*dtm; \
            di=c5-c0; dt=d5-d0; dtm=fzx *dt; s8 +=di*dtm; r8 +=dt*dtm; \
            di=c4-c3; dt=d4-d3; dtm=fzyx*dt; s9 +=di*dtm; r9 +=dt*dtm; \
            di=c6-c1; dt=d6-d1; dtm=fzyx*dt; s10+=di*dtm; r10+=dt*dtm; \
            di=c7-c0; dt=d7-d0; dtm=fzyx*dt; s11+=di*dtm; r11+=dt*dtm; \
            di=c5-c2; dt=d5-d2; dtm=fzyx*dt; s12+=di*dtm; r12+=dt*dtm; \
            bces += d0*__logf(c0) + (1.0f - d0)*__logf(1.0f - c0); \
        } while (0)

        PROC_ELEM(i00.x,i00.y,i01.x,i01.y,i10.x,i10.y,i11.x,i11.y,
                  t00.x,t00.y,t01.x,t01.y,t10.x,t10.y,t11.x,t11.y, 1.0f);
        PROC_ELEM(i00.y,i00.z,i01.y,i01.z,i10.y,i10.z,i11.y,i11.z,
                  t00.y,t00.z,t01.y,t01.z,t10.y,t10.z,t11.y,t11.z, 1.0f);
        PROC_ELEM(i00.z,i00.w,i01.z,i01.w,i10.z,i10.w,i11.z,i11.w,
                  t00.z,t00.w,t01.z,t01.w,t10.z,t10.w,t11.z,t11.w, 1.0f);
        PROC_ELEM(i00.w,i00e, i01.w,i01e, i10.w,i10e, i11.w,i11e,
                  t00.w,t00e, t01.w,t01e, t10.w,t10e, t11.w,t11e, fx3);
        #undef PROC_ELEM
    }

    // block reduction: wave shuffle -> LDS -> 27 double atomics
    float vals[27] = {s0,s1,s2,s3,s4,s5,s6,s7,s8,s9,s10,s11,s12,
                      r0,r1,r2,r3,r4,r5,r6,r7,r8,r9,r10,r11,r12, bces};
    #pragma unroll
    for (int k = 0; k < 27; k++) vals[k] = wred(vals[k]);

    __shared__ float red[4][27];
    int lane = threadIdx.x & 63;
    int wave = threadIdx.x >> 6;
    if (lane == 0) {
        #pragma unroll
        for (int k = 0; k < 27; k++) red[wave][k] = vals[k];
    }
    __syncthreads();
    if (threadIdx.x < 27) {
        float t = red[0][threadIdx.x] + red[1][threadIdx.x]
                + red[2][threadIdx.x] + red[3][threadIdx.x];
        atomicAdd(&acc[threadIdx.x], (double)t);
    }
}

__global__ void gc3d_final(const double* __restrict__ acc, float* __restrict__ out) {
    if (threadIdx.x == 0 && blockIdx.x == 0) {
        double s = 0.0;
        #pragma unroll
        for (int k = 0; k < 13; k++) s += acc[k] / (acc[13 + k] + 1e-5);
        double bce = -acc[26] / (double)NTOT;
        out[0] = (float)(bce + 1.0 - s / 13.0);
    }
}

extern "C" void kernel_launch(void* const* d_in, const int* in_sizes, int n_in,
                              void* d_out, int out_size, void* d_ws, size_t ws_size,
                              hipStream_t stream) {
    const float* inp = (const float*)d_in[0];
    const float* tgt = (const float*)d_in[1];
    double* acc = (double*)d_ws;

    hipMemsetAsync(d_ws, 0, 27 * sizeof(double), stream);
    gc3d_main<<<1536, 256, 0, stream>>>(inp, tgt, acc);
    gc3d_final<<<1, 64, 0, stream>>>(acc, (float*)d_out);
}